// Round 10
// baseline (884.013 us; speedup 1.0000x reference)
//
#include <hip/hip_runtime.h>
#include <math.h>
#include <stdint.h>

#define TT 672
#define NFREQ 337
#define DM 128
#define DFF 256
#define QP_CWT 5456   // 8 * (672+10)
#define QPB 2048      // branch padded-row interior
#define GRD 288       // guard rows each side of every B image
#define QSC_ALL 6032  // 288 + 5456 + 288
#define QSB_ALL 2624  // 288 + 2048 + 288
#define BROWS 288     // B LDS rows per buffer (4 waves x 72)
#define ROWSP 9552    // 5456 + 2048 + 2048 partial rows per batch

typedef float f32x4 __attribute__((ext_vector_type(4)));
typedef short short8 __attribute__((ext_vector_type(8)));

struct FiltParams { int L[8]; int off[8]; int doff[8]; };

__device__ inline unsigned short f2b(float f) {
  unsigned u = __float_as_uint(f);
  return (unsigned short)((u + 0x7FFFu + ((u >> 16) & 1u)) >> 16);
}
__device__ inline float b2f(unsigned short s) {
  return __uint_as_float(((unsigned)s) << 16);
}

__device__ inline void gld16(const void* g, void* l) {
  __builtin_amdgcn_global_load_lds(
      (const __attribute__((address_space(1))) unsigned int*)g,
      (__attribute__((address_space(3))) unsigned int*)l, 16, 0, 0);
}

// ---------------- DFT: fl2d[b][f] = mean_n |X[b,f,n]| ----------------
__global__ void k_dft(const float* __restrict__ x, float* __restrict__ fl2d) {
  __shared__ float ct[TT], st[TT];
  __shared__ float red[128];
  int f = blockIdx.x, b = blockIdx.y, n = threadIdx.x;
  for (int k = n; k < TT; k += 128) {
    float th = (float)(6.283185307179586 * (double)k / 672.0);
    ct[k] = cosf(th); st[k] = sinf(th);
  }
  __syncthreads();
  float re = 0.f, im = 0.f;
  const float* xb = x + ((size_t)b * TT) * DM + n;
  int k = 0;
  for (int t = 0; t < TT; ++t) {
    float xv = xb[(size_t)t * DM];
    re += xv * ct[k]; im += xv * st[k];
    k += f; if (k >= TT) k -= TT;
  }
  red[n] = sqrtf(re * re + im * im);
  __syncthreads();
  for (int s = 64; s > 0; s >>= 1) { if (n < s) red[n] += red[n + s]; __syncthreads(); }
  if (n == 0) fl2d[b * NFREQ + f] = red[0] * (1.f / 128.f);
}

// ---------------- control ----------------
__global__ void k_ctrl(const float* __restrict__ fl2d,
                       const float* __restrict__ b1, const float* __restrict__ b2,
                       int* __restrict__ ctrl, float* __restrict__ wsm,
                       float* __restrict__ b1e, float* __restrict__ b2e) {
  __shared__ float fl[NFREQ];
  int tid = threadIdx.x;
  for (int f = tid; f < NFREQ; f += 256) {
    float s = 0.f;
    for (int b = 0; b < 8; ++b) s += fl2d[b * NFREQ + f];
    fl[f] = s * 0.125f;
  }
  __syncthreads();
  if (tid == 0) {
    fl[0] = 0.f;
    int t1 = 1; float v1 = fl[1];
    for (int f = 2; f < NFREQ; ++f) if (fl[f] > v1) { v1 = fl[f]; t1 = f; }
    int t2 = (t1 == 1) ? 2 : 1; float v2 = fl[t2];
    for (int f = t2 + 1; f < NFREQ; ++f) { if (f == t1) continue; if (fl[f] > v2) { v2 = fl[f]; t2 = f; } }
    int tops[2] = { t1, t2 };
    for (int kk = 0; kk < 2; ++kk) {
      int p = TT / tops[kk];
      int H = (TT + p - 1) / p;
      int PW = p - 1 < 5 ? p - 1 : 5;
      ctrl[kk * 3 + 0] = p; ctrl[kk * 3 + 1] = PW; ctrl[kk * 3 + 2] = H * (p + 2 * PW);
    }
    ctrl[6] = 672; ctrl[7] = 8; ctrl[8] = QP_CWT;
    for (int b = 0; b < 8; ++b) {
      float p0 = fl2d[b * NFREQ + t1], p1 = fl2d[b * NFREQ + t2];
      float m = fmaxf(p0, p1);
      float e0 = expf(p0 - m), e1 = expf(p1 - m);
      float inv = 1.f / (e0 + e1);
      wsm[b * 2 + 0] = e0 * inv; wsm[b * 2 + 1] = e1 * inv;
    }
  }
  if (tid < 256) { float s = 0.f; for (int i = 0; i < 6; ++i) s += b1[i * DFF + tid]; b1e[tid] = s * (1.f / 6.f); }
  if (tid < 128) { float s = 0.f; for (int i = 0; i < 6; ++i) s += b2[i * DM + tid]; b2e[tid] = s * (1.f / 6.f); }
}

// ---------------- effective weights -> bf16, pre-swizzled slab layout ----------------
__global__ void k_wprep(const float* __restrict__ W, unsigned short* __restrict__ wl,
                        int Cout, int Cin) {
  int co = blockIdx.x, ci = blockIdx.y, t = threadIdx.x;
  if (t >= 121) return;
  int u = t / 11, v = t - u * 11;
  int du = u - 5; if (du < 0) du = -du;
  int dv = v - 5; if (dv < 0) dv = -dv;
  int m = du > dv ? du : dv;
  size_t kstride = (size_t)Cout * Cin * 121;
  size_t base = ((size_t)co * Cin + ci) * 121 + t;
  float s = 0.f;
  for (int i = m; i < 6; ++i) s += W[i * kstride + base];
  int cot = co >> 7, row = co & 127;
  int c64 = ci >> 6, part = (ci >> 3) & 7, within = ci & 7;
  int nc = Cin >> 6;
  size_t slab = ((size_t)t * (Cout >> 7) + cot) * nc + c64;
  wl[slab * 8192 + row * 64 + (((part ^ (row & 7)) << 3) + within)] = f2b(s * (1.f / 6.f));
}

// ---------------- FIR filters (psi fused in) ----------------
__global__ void k_filt(float* __restrict__ d, FiltParams fp) {
  __shared__ double ps[1024];
  __shared__ float ip[1024];
  int si = blockIdx.x, tid = threadIdx.x;
  for (int i = tid; i < 1024; i += 256) {
    double xv = -8.0 + (double)i * (16.0 / 1023.0);
    ps[i] = exp(-xv * xv * 0.5) * cos(5.0 * xv);
  }
  __syncthreads();
  if (tid == 0) {
    double acc = 0.0;
    for (int i = 0; i < 1024; ++i) { acc += ps[i]; ip[i] = (float)(acc * (16.0 / 1023.0)); }
  }
  __syncthreads();
  double texp = (si == 7) ? 8.0 : (-1.0 + (double)si * (9.0 / 7.0));
  double s = pow(2.0, texp);
  double sstep = s * (16.0 / 1023.0);
  double sq = sqrt(s);
  int L = fp.L[si];
  float* dd = d + fp.doff[si];
  for (int k = tid; k <= L; k += 256) {
    float fk = 0.f, fkm = 0.f;
    if (k < L) { int j = (int)((double)k / sstep); if (j > 1023) j = 1023; fk = ip[j]; }
    if (k > 0) { int j = (int)((double)(k - 1) / sstep); if (j > 1023) j = 1023; fkm = ip[j]; }
    dd[k] = (float)(-sq * (double)(fkm - fk));
  }
}

// ---------------- CWT -> padded bf16 image coef_pad[b][q][n] ----------------
__global__ __launch_bounds__(256) void k_cwt(const float* __restrict__ x, const float* __restrict__ d,
                      unsigned short* __restrict__ coef, FiltParams fp) {
  __shared__ float dl[4130];
  int tile = blockIdx.x, si = blockIdx.y, b = blockIdx.z;
  int tid = threadIdx.x;
  int n = tid & 127, g = tid >> 7;
  int L = fp.L[si], off = fp.off[si];
  for (int i = tid; i < L + 33; i += 256) {
    int k = i - 16;
    dl[i] = ((unsigned)k <= (unsigned)L) ? d[fp.doff[si] + k] : 0.f;
  }
  __syncthreads();
  int ta = tile * 16 + g * 8;
  float acc[8];
  #pragma unroll
  for (int j = 0; j < 8; ++j) acc[j] = 0.f;
  int rlo = ta + off - L + 1; if (rlo < 0) rlo = 0;
  int rhi = ta + off + 9; if (rhi > TT) rhi = TT;
  const float* xb = x + ((size_t)b * TT) * DM + n;
  for (int r = rlo; r < rhi; ++r) {
    float xv = xb[(size_t)r * DM];
    int kb16 = 16 + r - ta - off + L - 1;
    #pragma unroll
    for (int j = 0; j < 8; ++j) acc[j] += dl[kb16 - j] * xv;
  }
  unsigned short* op = coef + ((size_t)b * QSC_ALL + (size_t)si * 682 + 5 + ta) * DM + n;
  #pragma unroll
  for (int j = 0; j < 8; ++j) op[(size_t)j * DM] = f2b(acc[j]);
}

// ---------------- build branch padded inputs (tight pad PW) ----------------
__global__ void k_xpad(const float* __restrict__ x, const int* __restrict__ ctrl,
                       unsigned short* __restrict__ xb0, unsigned short* __restrict__ xb1) {
  int q = blockIdx.x, b = blockIdx.y, n = threadIdx.x;
  for (int slot = 0; slot < 2; ++slot) {
    int p = ctrl[slot * 3], PW = ctrl[slot * 3 + 1], QP = ctrl[slot * 3 + 2];
    if (q >= QP) continue;
    int ppad = p + 2 * PW;
    int row = q / ppad, w = q - row * ppad;
    float val = 0.f;
    if (w >= PW && w < p + PW) {
      int t = row * p + (w - PW);
      if (t < TT) val = x[((size_t)b * TT + t) * DM + n];
    }
    unsigned short* dst = slot == 0 ? xb0 : xb1;
    dst[((size_t)b * QSB_ALL + q) * DM + n] = f2b(val);
  }
}

// ---------------- MFMA implicit-GEMM conv: pipe-balanced + async B pipeline ----------------
// grid = 8 * 72; b = bid&7 (XCD pin); r = bid>>3:
//   r < 44: CWT  zz = r/22, tile = r%22
//   r < 58: br0  zz = (r-44)/7, tile = (r-44)%7
//   r < 72: br1  zz = (r-58)/7, tile = (r-58)%7
// 256 thr = 4 waves; block 128co x 256q; wave 64co x 128q (acc 4x8).
// B: double-buffered LDS, staged via swizzled-source global_load_lds (guards make
// OOB reads zero); ONE barrier per (cc,u); next tile prefetched under compute.
// A: direct from pre-swizzled global slabs (VMEM pipe).
__global__ __launch_bounds__(256, 2) void k_convm(
    const unsigned short* __restrict__ inC, const unsigned short* __restrict__ in0,
    const unsigned short* __restrict__ in1, const unsigned short* __restrict__ wl,
    const float* __restrict__ bias,
    unsigned short* __restrict__ outC, unsigned short* __restrict__ out0,
    unsigned short* __restrict__ out1, unsigned short* __restrict__ partial,
    const int* __restrict__ ctrl, int Cin, int Cout,
    int QSC, int QSB, int doGelu, int mode)
{
  __shared__ __align__(16) unsigned short Blds[2][BROWS * 64];  // 2 x 36 KB

  int bid = blockIdx.x;
  int b = bid & 7;
  int r = bid >> 3;
  int job, zz, tile;
  if (r < 44) { job = 2; zz = r / 22; tile = r - zz * 22; }
  else if (r < 58) { int rr = r - 44; job = 0; zz = rr / 7; tile = rr - zz * 7; }
  else { int rr = r - 58; job = 1; zz = rr / 7; tile = rr - zz * 7; }

  int p, QP, PW;
  if (job == 2) { p = 672; PW = 5; QP = QP_CWT; }
  else { p = ctrl[job * 3]; PW = ctrl[job * 3 + 1]; QP = ctrl[job * 3 + 2]; }
  int ppad = p + 2 * PW;
  int q0 = tile * 256;
  if (q0 >= QP) return;

  const unsigned short* in = job == 2 ? inC : (job == 0 ? in0 : in1);
  int QS = job == 2 ? QSC : QSB;
  int jobbase = job == 2 ? 0 : (job == 0 ? QP_CWT : QP_CWT + QPB);

  int nc = Cin >> 6, ncot = Cout >> 7;
  int cotblk, c64lo, ncc;
  if (mode == 0) { cotblk = zz; c64lo = 0; ncc = nc; }
  else { cotblk = 0; c64lo = zz * 2; ncc = 2; }

  int tid = threadIdx.x;
  int wv = tid >> 6, lane = tid & 63;
  int wcx = wv & 1, wqy = wv >> 1;
  int lrow = lane & 15, lhi = lane >> 4;
  int nv = 2 * PW;
  size_t vstride = (size_t)ncot * nc * 16384;
  int CinB = Cin * 2;

  // A byte offsets within a slab (per ks half)
  int aoff0 = (wcx * 64 + lrow) * 128 + ((lhi ^ (lrow & 7)) << 4);
  int aoff1 = (wcx * 64 + lrow) * 128 + (((4 + lhi) ^ (lrow & 7)) << 4);

  // B staging lane constants (swizzled global source, linear LDS dest)
  int rsub = lane >> 3;                      // 0..7
  int psrc = (lane & 7) ^ (rsub & 7);        // source part for this lane
  const char* inG = (const char*)(in + (size_t)b * QS * Cin);

  f32x4 acc[4][8];
  #pragma unroll
  for (int i = 0; i < 4; ++i)
    #pragma unroll
    for (int j = 0; j < 8; ++j)
      #pragma unroll
      for (int rr = 0; rr < 4; ++rr) acc[i][j][rr] = 0.f;

  int kkN = ncc * 11;
  // pipeline over valid (cc,u) stages
  int kk = 0, qb0c = 0, c64c = 0, uc = 0;
  auto valid = [&](int k, int& qb0o, int& c64o, int& uo) -> bool {
    int ccl = k / 11; int ul = k - ccl * 11;
    qb0o = q0 - PW + (ul - 5) * ppad;
    c64o = c64lo + ccl; uo = ul;
    return !(qb0o >= QP || qb0o + 256 + 2 * PW <= 0);
  };
  while (kk < kkN && !valid(kk, qb0c, c64c, uc)) ++kk;
  int cur = 0;
  if (kk < kkN) {
    // stage first tile into buf 0
    const char* src = inG + (ptrdiff_t)(qb0c + wv * 72 + rsub) * CinB + c64c * 128 + psrc * 16;
    unsigned short* ldsb = &Blds[0][(wv * 72) * 64];
    #pragma unroll
    for (int i = 0; i < 9; ++i)
      gld16(src + (ptrdiff_t)i * 8 * CinB, (char*)ldsb + i * 1024);
  }
  while (kk < kkN) {
    int kn = kk + 1, qb0n = 0, c64n_ = 0, un = 0;
    while (kn < kkN && !valid(kn, qb0n, c64n_, un)) ++kn;
    __syncthreads();   // drains this buffer's gld16s (issued long ago)
    if (kn < kkN) {
      const char* src = inG + (ptrdiff_t)(qb0n + wv * 72 + rsub) * CinB + c64n_ * 128 + psrc * 16;
      unsigned short* ldsb = &Blds[cur ^ 1][(wv * 72) * 64];
      #pragma unroll
      for (int i = 0; i < 9; ++i)
        gld16(src + (ptrdiff_t)i * 8 * CinB, (char*)ldsb + i * 1024);
    }
    // compute on buf[cur]
    const unsigned short* Bcur = &Blds[cur][0];
    size_t slab0b = ((size_t)((uc * 11 + 5 - PW) * ncot + cotblk) * nc + c64c) * 16384;
    const char* aglb = (const char*)wl + slab0b;
    for (int vi = 0; vi <= nv; ++vi) {
      short8 a0[4], a1[4];
      #pragma unroll
      for (int mi = 0; mi < 4; ++mi)
        a0[mi] = *(const short8*)(aglb + aoff0 + mi * 2048);
      #pragma unroll
      for (int mi = 0; mi < 4; ++mi)
        a1[mi] = *(const short8*)(aglb + aoff1 + mi * 2048);
      __builtin_amdgcn_s_setprio(1);
      {
        short8 bf[8];
        #pragma unroll
        for (int ni = 0; ni < 8; ++ni) {
          int row = wqy * 128 + ni * 16 + lrow + vi;
          bf[ni] = *(const short8*)&Bcur[row * 64 + ((lhi ^ (row & 7)) << 3)];
        }
        #pragma unroll
        for (int mi = 0; mi < 4; ++mi)
          #pragma unroll
          for (int ni = 0; ni < 8; ++ni)
            acc[mi][ni] = __builtin_amdgcn_mfma_f32_16x16x32_bf16(a0[mi], bf[ni], acc[mi][ni], 0, 0, 0);
      }
      {
        short8 bf[8];
        #pragma unroll
        for (int ni = 0; ni < 8; ++ni) {
          int row = wqy * 128 + ni * 16 + lrow + vi;
          bf[ni] = *(const short8*)&Bcur[row * 64 + (((4 + lhi) ^ (row & 7)) << 3)];
        }
        #pragma unroll
        for (int mi = 0; mi < 4; ++mi)
          #pragma unroll
          for (int ni = 0; ni < 8; ++ni)
            acc[mi][ni] = __builtin_amdgcn_mfma_f32_16x16x32_bf16(a1[mi], bf[ni], acc[mi][ni], 0, 0, 0);
      }
      __builtin_amdgcn_s_setprio(0);
      aglb += vstride;
    }
    cur ^= 1; kk = kn; qb0c = qb0n; c64c = c64n_; uc = un;
  }

  if (mode == 0) {
    unsigned short* outp = job == 2 ? outC : (job == 0 ? out0 : out1);
    int qv[8]; bool pad[8];
    #pragma unroll
    for (int ni = 0; ni < 8; ++ni) {
      int q = q0 + wqy * 128 + ni * 16 + lrow;
      qv[ni] = q;
      int w = q - (q / ppad) * ppad;
      pad[ni] = (w < PW) || (w >= p + PW);
    }
    #pragma unroll
    for (int mi = 0; mi < 4; ++mi) {
      int co = cotblk * 128 + wcx * 64 + mi * 16 + lhi * 4;
      float bv0 = bias[co], bv1 = bias[co + 1], bv2 = bias[co + 2], bv3 = bias[co + 3];
      #pragma unroll
      for (int ni = 0; ni < 8; ++ni) {
        int q = qv[ni];
        if (q >= QP) continue;
        float v0 = acc[mi][ni][0] + bv0;
        float v1 = acc[mi][ni][1] + bv1;
        float v2 = acc[mi][ni][2] + bv2;
        float v3 = acc[mi][ni][3] + bv3;
        if (doGelu) {
          v0 = 0.5f * v0 * (1.f + erff(v0 * 0.7071067811865476f));
          v1 = 0.5f * v1 * (1.f + erff(v1 * 0.7071067811865476f));
          v2 = 0.5f * v2 * (1.f + erff(v2 * 0.7071067811865476f));
          v3 = 0.5f * v3 * (1.f + erff(v3 * 0.7071067811865476f));
        }
        if (pad[ni]) { v0 = 0.f; v1 = 0.f; v2 = 0.f; v3 = 0.f; }
        uint2 pk;
        pk.x = (unsigned)f2b(v0) | ((unsigned)f2b(v1) << 16);
        pk.y = (unsigned)f2b(v2) | ((unsigned)f2b(v3) << 16);
        *(uint2*)&outp[((size_t)b * QS + q) * Cout + co] = pk;
      }
    }
  } else {
    unsigned short* pp = partial + (size_t)zz * 8 * ROWSP * 128;
    #pragma unroll
    for (int mi = 0; mi < 4; ++mi) {
      int co = wcx * 64 + mi * 16 + lhi * 4;
      #pragma unroll
      for (int ni = 0; ni < 8; ++ni) {
        int q = q0 + wqy * 128 + ni * 16 + lrow;
        if (q >= QP) continue;
        uint2 pk;
        pk.x = (unsigned)f2b(acc[mi][ni][0]) | ((unsigned)f2b(acc[mi][ni][1]) << 16);
        pk.y = (unsigned)f2b(acc[mi][ni][2]) | ((unsigned)f2b(acc[mi][ni][3]) << 16);
        *(uint2*)&pp[((size_t)b * ROWSP + jobbase + q) * 128 + co] = pk;
      }
    }
  }
}

// ---------------- final combine (fuses split-K reduce + conv2 bias) ----------------
__global__ void k_combine(const float* __restrict__ x, const unsigned short* __restrict__ P,
    const float* __restrict__ b2e,
    const float* __restrict__ Wsc, const float* __restrict__ bsc,
    const float* __restrict__ wsm, const int* __restrict__ ctrl, float* __restrict__ out) {
  int t = blockIdx.x, b = blockIdx.y, n = threadIdx.x;
  const size_t SL = (size_t)8 * ROWSP * 128;
  const unsigned short* P0 = P;
  const unsigned short* P1 = P + SL;
  float bv = b2e[n];
  float accv = bsc[n];
  #pragma unroll
  for (int s = 0; s < 8; ++s) {
    size_t r = ((size_t)b * ROWSP + (size_t)s * 682 + 5 + t) * 128 + n;
    float wr = b2f(P0[r]) + b2f(P1[r]) + bv;
    accv += wr * Wsc[n * 8 + s];
  }
  int p0 = ctrl[0], PW0 = ctrl[1], p1 = ctrl[3], PW1 = ctrl[4];
  int q0 = (t / p0) * (p0 + 2 * PW0) + PW0 + (t % p0);
  int q1 = (t / p1) * (p1 + 2 * PW1) + PW1 + (t % p1);
  size_t r0 = ((size_t)b * ROWSP + QP_CWT + q0) * 128 + n;
  size_t r1 = ((size_t)b * ROWSP + QP_CWT + QPB + q1) * 128 + n;
  float bo0v = b2f(P0[r0]) + b2f(P1[r0]) + bv;
  float bo1v = b2f(P0[r1]) + b2f(P1[r1]) + bv;
  float po = wsm[b * 2 + 0] * bo0v + wsm[b * 2 + 1] * bo1v;
  size_t xi = ((size_t)b * TT + t) * DM + n;
  out[xi] = 0.6513215599f * accv + 0.3486784401f * po + x[xi];
}

extern "C" void kernel_launch(void* const* d_in, const int* in_sizes, int n_in,
                              void* d_out, int out_size, void* d_ws, size_t ws_size,
                              hipStream_t stream) {
  const float* x   = (const float*)d_in[0];
  const float* W1  = (const float*)d_in[1];
  const float* b1  = (const float*)d_in[2];
  const float* W2  = (const float*)d_in[3];
  const float* b2  = (const float*)d_in[4];
  const float* Wsc = (const float*)d_in[5];
  const float* bsc = (const float*)d_in[6];
  float* out = (float*)d_out;

  char* base = (char*)d_ws;
  size_t off = 0;
  auto alloc = [&](size_t bytes) -> void* {
    void* pp = base + off; off = (off + bytes + 255) & ~(size_t)255; return pp;
  };
  int*   ctrl = (int*)  alloc(32 * 4);
  float* wsm  = (float*)alloc(16 * 4);
  float* b1e  = (float*)alloc(256 * 4);
  float* b2e  = (float*)alloc(128 * 4);
  float* fl2d = (float*)alloc((size_t)8 * NFREQ * 4);
  float* filt = (float*)alloc(8192 * 4);
  unsigned short* wl1  = (unsigned short*)alloc((size_t)121 * 2 * 2 * 8192 * 2);
  unsigned short* wl2  = (unsigned short*)alloc((size_t)121 * 1 * 4 * 8192 * 2);
  unsigned short* coefA= (unsigned short*)alloc((size_t)8 * QSC_ALL * DM * 2);
  unsigned short* h1pA = (unsigned short*)alloc((size_t)8 * QSC_ALL * DFF * 2);
  unsigned short* h1b0A= (unsigned short*)alloc((size_t)8 * QSB_ALL * DFF * 2);
  unsigned short* h1b1A= (unsigned short*)alloc((size_t)8 * QSB_ALL * DFF * 2);
  unsigned short* xb0A = (unsigned short*)alloc((size_t)8 * QSB_ALL * DM * 2);
  unsigned short* xb1A = (unsigned short*)alloc((size_t)8 * QSB_ALL * DM * 2);
  unsigned short* P    = (unsigned short*)alloc((size_t)2 * 8 * ROWSP * 128 * 2);

  // interior pointers (past the 288-row guard)
  unsigned short* coefp = coefA + (size_t)GRD * DM;
  unsigned short* h1p   = h1pA  + (size_t)GRD * DFF;
  unsigned short* h1b0  = h1b0A + (size_t)GRD * DFF;
  unsigned short* h1b1  = h1b1A + (size_t)GRD * DFF;
  unsigned short* xb0   = xb0A  + (size_t)GRD * DM;
  unsigned short* xb1   = xb1A  + (size_t)GRD * DM;

  FiltParams fp;
  {
    double step = 16.0 / 1023.0;
    int doff = 0;
    for (int i = 0; i < 8; ++i) {
      double t = (i == 7) ? 8.0 : (-1.0 + (double)i * (9.0 / 7.0));
      double s = pow(2.0, t);
      double stop = s * 16.0 + 1.0;
      int nmax = (int)ceil(stop);
      double sstep = s * step;
      int L = 0;
      for (int k = 0; k < nmax; ++k) {
        long j = (long)((double)k / sstep);
        if (j < 1024) L++; else break;
      }
      fp.L[i] = L;
      fp.off[i] = (L - 2) / 2;
      fp.doff[i] = doff;
      doff += L + 1;
    }
  }

  // zero all guard-padded B images (guards + interior; producers overwrite interior)
  hipMemsetAsync(coefA, 0, (size_t)8 * QSC_ALL * DM * 2, stream);
  hipMemsetAsync(h1pA,  0, (size_t)8 * QSC_ALL * DFF * 2, stream);
  hipMemsetAsync(h1b0A, 0, (size_t)8 * QSB_ALL * DFF * 2, stream);
  hipMemsetAsync(h1b1A, 0, (size_t)8 * QSB_ALL * DFF * 2, stream);
  hipMemsetAsync(xb0A,  0, (size_t)8 * QSB_ALL * DM * 2, stream);
  hipMemsetAsync(xb1A,  0, (size_t)8 * QSB_ALL * DM * 2, stream);

  k_dft<<<dim3(NFREQ, 8), 128, 0, stream>>>(x, fl2d);
  k_ctrl<<<1, 256, 0, stream>>>(fl2d, b1, b2, ctrl, wsm, b1e, b2e);
  k_wprep<<<dim3(256, 128), 128, 0, stream>>>(W1, wl1, 256, 128);
  k_wprep<<<dim3(128, 256), 128, 0, stream>>>(W2, wl2, 128, 256);
  k_filt<<<8, 256, 0, stream>>>(filt, fp);
  k_cwt<<<dim3(42, 8, 8), 256, 0, stream>>>(x, filt, coefp, fp);
  k_xpad<<<dim3(QPB, 8), 128, 0, stream>>>(x, ctrl, xb0, xb1);

  // conv1 (mode 0): {coefp, xb0, xb1} -> {h1p, h1b0, h1b1}, gelu
  k_convm<<<576, 256, 0, stream>>>(coefp, xb0, xb1, wl1, b1e,
      h1p, h1b0, h1b1, (unsigned short*)nullptr, ctrl, 128, 256, QSC_ALL, QSB_ALL, 1, 0);
  // conv2 (mode 1): {h1p, h1b0, h1b1} -> partial P
  k_convm<<<576, 256, 0, stream>>>(h1p, h1b0, h1b1, wl2, b2e,
      (unsigned short*)nullptr, (unsigned short*)nullptr, (unsigned short*)nullptr, P,
      ctrl, 256, 128, QSC_ALL, QSB_ALL, 0, 1);

  k_combine<<<dim3(TT, 8), 128, 0, stream>>>(x, P, b2e, Wsc, bsc, wsm, ctrl, out);
}

// Round 11
// 776.555 us; speedup vs baseline: 1.1384x; 1.1384x over previous
//
#include <hip/hip_runtime.h>
#include <math.h>
#include <stdint.h>

#define TT 672
#define NFREQ 337
#define DM 128
#define DFF 256
#define QP_CWT 5456   // 8 * (672+10)
#define QPB 2048      // branch padded-row allocation stride
#define BROWS 272     // B LDS rows (256 q + up to 10 halo)
#define ROWSP 9552    // 5456 + 2048 + 2048 partial row space per batch
#define FPAD 32       // zero-pad on each side of every FIR filter

typedef float f32x4 __attribute__((ext_vector_type(4)));
typedef short short8 __attribute__((ext_vector_type(8)));

struct FiltParams { int L[8]; int off[8]; int doff[8]; };

__device__ inline unsigned short f2b(float f) {
  unsigned u = __float_as_uint(f);
  return (unsigned short)((u + 0x7FFFu + ((u >> 16) & 1u)) >> 16);
}
__device__ inline float b2f(unsigned short s) {
  return __uint_as_float(((unsigned)s) << 16);
}

// ---------------- DFT: fl2d[b][f] = mean_n |X[b,f,n]| ----------------
__global__ void k_dft(const float* __restrict__ x, float* __restrict__ fl2d) {
  __shared__ float ct[TT], st[TT];
  __shared__ float red[128];
  int f = blockIdx.x, b = blockIdx.y, n = threadIdx.x;
  for (int k = n; k < TT; k += 128) {
    float th = (float)(6.283185307179586 * (double)k / 672.0);
    ct[k] = cosf(th); st[k] = sinf(th);
  }
  __syncthreads();
  float re = 0.f, im = 0.f;
  const float* xb = x + ((size_t)b * TT) * DM + n;
  int k = 0;
  for (int t = 0; t < TT; ++t) {
    float xv = xb[(size_t)t * DM];
    re += xv * ct[k]; im += xv * st[k];
    k += f; if (k >= TT) k -= TT;
  }
  red[n] = sqrtf(re * re + im * im);
  __syncthreads();
  for (int s = 64; s > 0; s >>= 1) { if (n < s) red[n] += red[n + s]; __syncthreads(); }
  if (n == 0) fl2d[b * NFREQ + f] = red[0] * (1.f / 128.f);
}

// ---------------- control ----------------
__global__ void k_ctrl(const float* __restrict__ fl2d,
                       const float* __restrict__ b1, const float* __restrict__ b2,
                       int* __restrict__ ctrl, float* __restrict__ wsm,
                       float* __restrict__ b1e, float* __restrict__ b2e) {
  __shared__ float fl[NFREQ];
  int tid = threadIdx.x;
  for (int f = tid; f < NFREQ; f += 256) {
    float s = 0.f;
    for (int b = 0; b < 8; ++b) s += fl2d[b * NFREQ + f];
    fl[f] = s * 0.125f;
  }
  __syncthreads();
  if (tid == 0) {
    fl[0] = 0.f;
    int t1 = 1; float v1 = fl[1];
    for (int f = 2; f < NFREQ; ++f) if (fl[f] > v1) { v1 = fl[f]; t1 = f; }
    int t2 = (t1 == 1) ? 2 : 1; float v2 = fl[t2];
    for (int f = t2 + 1; f < NFREQ; ++f) { if (f == t1) continue; if (fl[f] > v2) { v2 = fl[f]; t2 = f; } }
    int tops[2] = { t1, t2 };
    for (int kk = 0; kk < 2; ++kk) {
      int p = TT / tops[kk];
      int H = (TT + p - 1) / p;
      int PW = p - 1 < 5 ? p - 1 : 5;
      ctrl[kk * 3 + 0] = p; ctrl[kk * 3 + 1] = PW; ctrl[kk * 3 + 2] = H * (p + 2 * PW);
    }
    ctrl[6] = 672; ctrl[7] = 8; ctrl[8] = QP_CWT;
    for (int b = 0; b < 8; ++b) {
      float p0 = fl2d[b * NFREQ + t1], p1 = fl2d[b * NFREQ + t2];
      float m = fmaxf(p0, p1);
      float e0 = expf(p0 - m), e1 = expf(p1 - m);
      float inv = 1.f / (e0 + e1);
      wsm[b * 2 + 0] = e0 * inv; wsm[b * 2 + 1] = e1 * inv;
    }
  }
  if (tid < 256) { float s = 0.f; for (int i = 0; i < 6; ++i) s += b1[i * DFF + tid]; b1e[tid] = s * (1.f / 6.f); }
  if (tid < 128) { float s = 0.f; for (int i = 0; i < 6; ++i) s += b2[i * DM + tid]; b2e[tid] = s * (1.f / 6.f); }
}

// ---------------- effective weights -> bf16, pre-swizzled slab layout ----------------
// wl[((uv*(Cout/128)+cot)*(Cin/64)+c64)][row=co&127][64 shorts, unit-swizzled]
__global__ void k_wprep(const float* __restrict__ W, unsigned short* __restrict__ wl,
                        int Cout, int Cin) {
  int co = blockIdx.x, ci = blockIdx.y, t = threadIdx.x;
  if (t >= 121) return;
  int u = t / 11, v = t - u * 11;
  int du = u - 5; if (du < 0) du = -du;
  int dv = v - 5; if (dv < 0) dv = -dv;
  int m = du > dv ? du : dv;
  size_t kstride = (size_t)Cout * Cin * 121;
  size_t base = ((size_t)co * Cin + ci) * 121 + t;
  float s = 0.f;
  for (int i = m; i < 6; ++i) s += W[i * kstride + base];
  int cot = co >> 7, row = co & 127;
  int c64 = ci >> 6, part = (ci >> 3) & 7, within = ci & 7;
  int nc = Cin >> 6;
  size_t slab = ((size_t)t * (Cout >> 7) + cot) * nc + c64;
  wl[slab * 8192 + row * 64 + (((part ^ (row & 7)) << 3) + within)] = f2b(s * (1.f / 6.f));
}

// ---------------- FIR filters (psi fused; zero-padded layout: [32 z][L+1][32 z]) ----------------
__global__ void k_filt(float* __restrict__ d, FiltParams fp) {
  __shared__ double ps[1024];
  __shared__ float ip[1024];
  int si = blockIdx.x, tid = threadIdx.x;
  for (int i = tid; i < 1024; i += 256) {
    double xv = -8.0 + (double)i * (16.0 / 1023.0);
    ps[i] = exp(-xv * xv * 0.5) * cos(5.0 * xv);
  }
  __syncthreads();
  if (tid == 0) {
    double acc = 0.0;
    for (int i = 0; i < 1024; ++i) { acc += ps[i]; ip[i] = (float)(acc * (16.0 / 1023.0)); }
  }
  __syncthreads();
  double texp = (si == 7) ? 8.0 : (-1.0 + (double)si * (9.0 / 7.0));
  double s = pow(2.0, texp);
  double sstep = s * (16.0 / 1023.0);
  double sq = sqrt(s);
  int L = fp.L[si];
  float* dd = d + fp.doff[si];
  // zero pads
  for (int k = tid; k < FPAD; k += 256) { dd[k] = 0.f; dd[FPAD + L + 1 + k] = 0.f; }
  for (int k = tid; k <= L; k += 256) {
    float fk = 0.f, fkm = 0.f;
    if (k < L) { int j = (int)((double)k / sstep); if (j > 1023) j = 1023; fk = ip[j]; }
    if (k > 0) { int j = (int)((double)(k - 1) / sstep); if (j > 1023) j = 1023; fkm = ip[j]; }
    dd[FPAD + k] = (float)(-sq * (double)(fkm - fk));
  }
}

// ---------------- CWT: register-window FIR, no LDS ----------------
// 128 threads (one per channel n), 16 taus per block. Filter taps are
// block-uniform -> direct (scalar-cached) loads from the padded global filter.
// 16-deep register window, unroll-16 static rotation; loop count padded to x16
// with guarded x-loads (zero terms are exact no-ops -> bitwise-identical).
__global__ __launch_bounds__(128) void k_cwt(const float* __restrict__ x, const float* __restrict__ d,
                      unsigned short* __restrict__ coef, FiltParams fp) {
  int tile = blockIdx.x, si = blockIdx.y, b = blockIdx.z;
  int n = threadIdx.x;
  int L = fp.L[si], off = fp.off[si];
  const float* dp = d + fp.doff[si] + FPAD;   // dp[i] valid for i in [-32, L+32]
  int ta = tile * 16;
  float acc[16];
  #pragma unroll
  for (int j = 0; j < 16; ++j) acc[j] = 0.f;
  int rlo = ta + off - L + 1; if (rlo < 0) rlo = 0;
  int rhi = ta + off + 17; if (rhi > TT) rhi = TT;
  int nt = rhi - rlo;
  int nt16 = (nt + 15) & ~15;
  int base0 = rlo - ta - off + L - 1;         // d-index for (r=rlo, j=0)
  // prime window: slot i holds dp[base0 + (i-16)]
  float w[16];
  #pragma unroll
  for (int i = 1; i < 16; ++i) w[i] = dp[base0 + i - 16];
  w[0] = 0.f;
  const float* xr = x + ((size_t)b * TT + rlo) * DM + n;
  for (int t = 0; t < nt16; t += 16) {
    #pragma unroll
    for (int tt = 0; tt < 16; ++tt) {
      int r = rlo + t + tt;
      w[tt] = dp[base0 + t + tt];
      float xv = (r < TT) ? xr[(size_t)(t + tt) * DM] : 0.f;
      #pragma unroll
      for (int j = 0; j < 16; ++j)
        acc[j] += w[(tt - j) & 15] * xv;
    }
  }
  unsigned short* op = coef + ((size_t)b * QP_CWT + (size_t)si * 682 + 5 + ta) * DM + n;
  #pragma unroll
  for (int j = 0; j < 16; ++j) op[(size_t)j * DM] = f2b(acc[j]);
  // fold in pad-row zeroing (replaces k_cwtpad)
  if (tile == 0) {
    unsigned short* pz = coef + ((size_t)b * QP_CWT + (size_t)si * 682) * DM + n;
    #pragma unroll
    for (int rr = 0; rr < 5; ++rr) pz[(size_t)rr * DM] = 0;
  } else if (tile == 41) {
    unsigned short* pz = coef + ((size_t)b * QP_CWT + (size_t)si * 682 + 677) * DM + n;
    #pragma unroll
    for (int rr = 0; rr < 5; ++rr) pz[(size_t)rr * DM] = 0;
  }
}

// ---------------- build branch padded inputs (tight pad PW) ----------------
__global__ void k_xpad(const float* __restrict__ x, const int* __restrict__ ctrl,
                       unsigned short* __restrict__ xb0, unsigned short* __restrict__ xb1) {
  int q = blockIdx.x, b = blockIdx.y, n = threadIdx.x;
  for (int slot = 0; slot < 2; ++slot) {
    int p = ctrl[slot * 3], PW = ctrl[slot * 3 + 1], QP = ctrl[slot * 3 + 2];
    if (q >= QP) continue;
    int ppad = p + 2 * PW;
    int row = q / ppad, w = q - row * ppad;
    float val = 0.f;
    if (w >= PW && w < p + PW) {
      int t = row * p + (w - PW);
      if (t < TT) val = x[((size_t)b * TT + t) * DM + n];
    }
    unsigned short* dst = slot == 0 ? xb0 : xb1;
    dst[((size_t)b * QPB + q) * DM + n] = f2b(val);
  }
}

// ---------------- MFMA implicit-GEMM conv: pipe-balanced (R9 structure) ----------------
// grid = 8 * 72 blocks; b = bid&7 (XCD pin); r = bid>>3:
//   r < 44: CWT  zz = r/22, tile = r%22
//   r < 58: br0  zz = (r-44)/7, tile = (r-44)%7
//   r < 72: br1  zz = (r-58)/7, tile = (r-58)%7
// 256 threads = 4 waves (2co x 2q); block tile 128co x 256q; wave 64co x 128q
// (acc 4x8 = 128 regs). B staged ONCE per (cc,u) in LDS; A direct from
// pre-swizzled global slabs (VMEM/L1 pipe, parallel to LDS pipe).
__global__ __launch_bounds__(256, 2) void k_convm(
    const unsigned short* __restrict__ inC, const unsigned short* __restrict__ in0,
    const unsigned short* __restrict__ in1, const unsigned short* __restrict__ wl,
    const float* __restrict__ bias,
    unsigned short* __restrict__ outC, unsigned short* __restrict__ out0,
    unsigned short* __restrict__ out1, unsigned short* __restrict__ partial,
    const int* __restrict__ ctrl, int Cin, int Cout,
    int QSC, int QSB, int doGelu, int mode)
{
  __shared__ __align__(16) unsigned short Blds[BROWS * 64];   // 34 KB

  int bid = blockIdx.x;
  int b = bid & 7;
  int r = bid >> 3;
  int job, zz, tile;
  if (r < 44) { job = 2; zz = r / 22; tile = r - zz * 22; }
  else if (r < 58) { int rr = r - 44; job = 0; zz = rr / 7; tile = rr - zz * 7; }
  else { int rr = r - 58; job = 1; zz = rr / 7; tile = rr - zz * 7; }

  int p, QP, PW;
  if (job == 2) { p = 672; PW = 5; QP = QP_CWT; }
  else { p = ctrl[job * 3]; PW = ctrl[job * 3 + 1]; QP = ctrl[job * 3 + 2]; }
  int ppad = p + 2 * PW;
  int q0 = tile * 256;
  if (q0 >= QP) return;

  const unsigned short* in = job == 2 ? inC : (job == 0 ? in0 : in1);
  int QS = job == 2 ? QSC : QSB;
  int jobbase = job == 2 ? 0 : (job == 0 ? QP_CWT : QP_CWT + QPB);

  int nc = Cin >> 6, ncot = Cout >> 7;
  int cotblk, c64lo, c64n;
  if (mode == 0) { cotblk = zz; c64lo = 0; c64n = nc; }
  else { cotblk = 0; c64lo = zz * 2; c64n = 2; }

  int tid = threadIdx.x;
  int wv = tid >> 6, lane = tid & 63;
  int wcx = wv & 1, wqy = wv >> 1;
  int lrow = lane & 15, lhi = lane >> 4;
  int nv = 2 * PW;
  size_t vstride = (size_t)ncot * nc * 16384;

  // lane-invariant byte offsets into a slab for the 2 ks halves
  int aoff0 = (wcx * 64 + lrow) * 128 + ((lhi ^ (lrow & 7)) << 4);
  int aoff1 = (wcx * 64 + lrow) * 128 + (((4 + lhi) ^ (lrow & 7)) << 4);

  f32x4 acc[4][8];
  #pragma unroll
  for (int i = 0; i < 4; ++i)
    #pragma unroll
    for (int j = 0; j < 8; ++j)
      #pragma unroll
      for (int rr = 0; rr < 4; ++rr) acc[i][j][rr] = 0.f;

  const unsigned short* inb = in + (size_t)b * QS * Cin;

  for (int cc = 0; cc < c64n; ++cc) {
    int c64 = c64lo + cc;
    for (int u = 0; u < 11; ++u) {
      int qb0 = q0 - PW + (u - 5) * ppad;
      if (qb0 >= QP || qb0 + 256 + 2 * PW <= 0) continue;  // block-uniform
      __syncthreads();
      // stage B once per (cc,u): 272 rows x 64ci, unit-swizzled
      #pragma unroll
      for (int it = 0; it < 9; ++it) {
        int idx = it * 256 + tid;
        if (idx < BROWS * 8) {
          int row = idx >> 3, part = idx & 7;
          int qs = qb0 + row;
          short8 vv = {0, 0, 0, 0, 0, 0, 0, 0};
          if ((unsigned)qs < (unsigned)QP)
            vv = *(const short8*)&inb[(size_t)qs * Cin + c64 * 64 + part * 8];
          *(short8*)&Blds[row * 64 + ((part ^ (row & 7)) << 3)] = vv;
        }
      }
      __syncthreads();
      size_t slab0b = ((size_t)((u * 11 + 5 - PW) * ncot + cotblk) * nc + c64) * 16384;
      const char* aglb = (const char*)wl + slab0b;
      for (int vi = 0; vi <= nv; ++vi) {
        // A frags direct from global (both ks) — VMEM pipe
        short8 a0[4], a1[4];
        #pragma unroll
        for (int mi = 0; mi < 4; ++mi)
          a0[mi] = *(const short8*)(aglb + aoff0 + mi * 2048);
        #pragma unroll
        for (int mi = 0; mi < 4; ++mi)
          a1[mi] = *(const short8*)(aglb + aoff1 + mi * 2048);
        __builtin_amdgcn_s_setprio(1);
        // ---- ks = 0 ----
        {
          short8 bf[8];
          #pragma unroll
          for (int ni = 0; ni < 8; ++ni) {
            int row = wqy * 128 + ni * 16 + lrow + vi;
            bf[ni] = *(const short8*)&Blds[row * 64 + ((lhi ^ (row & 7)) << 3)];
          }
          #pragma unroll
          for (int mi = 0; mi < 4; ++mi)
            #pragma unroll
            for (int ni = 0; ni < 8; ++ni)
              acc[mi][ni] = __builtin_amdgcn_mfma_f32_16x16x32_bf16(a0[mi], bf[ni], acc[mi][ni], 0, 0, 0);
        }
        // ---- ks = 1 ----
        {
          short8 bf[8];
          #pragma unroll
          for (int ni = 0; ni < 8; ++ni) {
            int row = wqy * 128 + ni * 16 + lrow + vi;
            bf[ni] = *(const short8*)&Blds[row * 64 + (((4 + lhi) ^ (row & 7)) << 3)];
          }
          #pragma unroll
          for (int mi = 0; mi < 4; ++mi)
            #pragma unroll
            for (int ni = 0; ni < 8; ++ni)
              acc[mi][ni] = __builtin_amdgcn_mfma_f32_16x16x32_bf16(a1[mi], bf[ni], acc[mi][ni], 0, 0, 0);
        }
        __builtin_amdgcn_s_setprio(0);
        aglb += vstride;
      }
    }
  }

  if (mode == 0) {
    unsigned short* outp = job == 2 ? outC : (job == 0 ? out0 : out1);
    int qv[8]; bool pad[8];
    #pragma unroll
    for (int ni = 0; ni < 8; ++ni) {
      int q = q0 + wqy * 128 + ni * 16 + lrow;
      qv[ni] = q;
      int w = q - (q / ppad) * ppad;
      pad[ni] = (w < PW) || (w >= p + PW);
    }
    #pragma unroll
    for (int mi = 0; mi < 4; ++mi) {
      int co = cotblk * 128 + wcx * 64 + mi * 16 + lhi * 4;
      float bv0 = bias[co], bv1 = bias[co + 1], bv2 = bias[co + 2], bv3 = bias[co + 3];
      #pragma unroll
      for (int ni = 0; ni < 8; ++ni) {
        int q = qv[ni];
        if (q >= QP) continue;
        float v0 = acc[mi][ni][0] + bv0;
        float v1 = acc[mi][ni][1] + bv1;
        float v2 = acc[mi][ni][2] + bv2;
        float v3 = acc[mi][ni][3] + bv3;
        if (doGelu) {
          v0 = 0.5f * v0 * (1.f + erff(v0 * 0.7071067811865476f));
          v1 = 0.5f * v1 * (1.f + erff(v1 * 0.7071067811865476f));
          v2 = 0.5f * v2 * (1.f + erff(v2 * 0.7071067811865476f));
          v3 = 0.5f * v3 * (1.f + erff(v3 * 0.7071067811865476f));
        }
        if (pad[ni]) { v0 = 0.f; v1 = 0.f; v2 = 0.f; v3 = 0.f; }
        uint2 pk;
        pk.x = (unsigned)f2b(v0) | ((unsigned)f2b(v1) << 16);
        pk.y = (unsigned)f2b(v2) | ((unsigned)f2b(v3) << 16);
        *(uint2*)&outp[((size_t)b * QS + q) * Cout + co] = pk;
      }
    }
  } else {
    unsigned short* pp = partial + (size_t)zz * 8 * ROWSP * 128;
    #pragma unroll
    for (int mi = 0; mi < 4; ++mi) {
      int co = wcx * 64 + mi * 16 + lhi * 4;
      #pragma unroll
      for (int ni = 0; ni < 8; ++ni) {
        int q = q0 + wqy * 128 + ni * 16 + lrow;
        if (q >= QP) continue;
        uint2 pk;
        pk.x = (unsigned)f2b(acc[mi][ni][0]) | ((unsigned)f2b(acc[mi][ni][1]) << 16);
        pk.y = (unsigned)f2b(acc[mi][ni][2]) | ((unsigned)f2b(acc[mi][ni][3]) << 16);
        *(uint2*)&pp[((size_t)b * ROWSP + jobbase + q) * 128 + co] = pk;
      }
    }
  }
}

// ---------------- final combine (fuses split-K reduce + conv2 bias) ----------------
__global__ void k_combine(const float* __restrict__ x, const unsigned short* __restrict__ P,
    const float* __restrict__ b2e,
    const float* __restrict__ Wsc, const float* __restrict__ bsc,
    const float* __restrict__ wsm, const int* __restrict__ ctrl, float* __restrict__ out) {
  int t = blockIdx.x, b = blockIdx.y, n = threadIdx.x;
  const size_t SL = (size_t)8 * ROWSP * 128;
  const unsigned short* P0 = P;
  const unsigned short* P1 = P + SL;
  float bv = b2e[n];
  float accv = bsc[n];
  #pragma unroll
  for (int s = 0; s < 8; ++s) {
    size_t r = ((size_t)b * ROWSP + (size_t)s * 682 + 5 + t) * 128 + n;
    float wr = b2f(P0[r]) + b2f(P1[r]) + bv;
    accv += wr * Wsc[n * 8 + s];
  }
  int p0 = ctrl[0], PW0 = ctrl[1], p1 = ctrl[3], PW1 = ctrl[4];
  int q0 = (t / p0) * (p0 + 2 * PW0) + PW0 + (t % p0);
  int q1 = (t / p1) * (p1 + 2 * PW1) + PW1 + (t % p1);
  size_t r0 = ((size_t)b * ROWSP + QP_CWT + q0) * 128 + n;
  size_t r1 = ((size_t)b * ROWSP + QP_CWT + QPB + q1) * 128 + n;
  float bo0v = b2f(P0[r0]) + b2f(P1[r0]) + bv;
  float bo1v = b2f(P0[r1]) + b2f(P1[r1]) + bv;
  float po = wsm[b * 2 + 0] * bo0v + wsm[b * 2 + 1] * bo1v;
  size_t xi = ((size_t)b * TT + t) * DM + n;
  out[xi] = 0.6513215599f * accv + 0.3486784401f * po + x[xi];
}

extern "C" void kernel_launch(void* const* d_in, const int* in_sizes, int n_in,
                              void* d_out, int out_size, void* d_ws, size_t ws_size,
                              hipStream_t stream) {
  const float* x   = (const float*)d_in[0];
  const float* W1  = (const float*)d_in[1];
  const float* b1  = (const float*)d_in[2];
  const float* W2  = (const float*)d_in[3];
  const float* b2  = (const float*)d_in[4];
  const float* Wsc = (const float*)d_in[5];
  const float* bsc = (const float*)d_in[6];
  float* out = (float*)d_out;

  char* base = (char*)d_ws;
  size_t off = 0;
  auto alloc = [&](size_t bytes) -> void* {
    void* pp = base + off; off = (off + bytes + 255) & ~(size_t)255; return pp;
  };
  int*   ctrl = (int*)  alloc(32 * 4);
  float* wsm  = (float*)alloc(16 * 4);
  float* b1e  = (float*)alloc(256 * 4);
  float* b2e  = (float*)alloc(128 * 4);
  float* fl2d = (float*)alloc((size_t)8 * NFREQ * 4);
  float* filt = (float*)alloc(8192 * 4);
  unsigned short* wl1  = (unsigned short*)alloc((size_t)121 * 2 * 2 * 8192 * 2);
  unsigned short* wl2  = (unsigned short*)alloc((size_t)121 * 1 * 4 * 8192 * 2);
  unsigned short* coefp= (unsigned short*)alloc((size_t)8 * QP_CWT * DM * 2);
  unsigned short* h1p  = (unsigned short*)alloc((size_t)8 * QP_CWT * DFF * 2);
  unsigned short* h1b0 = (unsigned short*)alloc((size_t)8 * QPB * DFF * 2);
  unsigned short* h1b1 = (unsigned short*)alloc((size_t)8 * QPB * DFF * 2);
  unsigned short* xb0  = (unsigned short*)alloc((size_t)8 * QPB * DM * 2);
  unsigned short* xb1  = (unsigned short*)alloc((size_t)8 * QPB * DM * 2);
  unsigned short* P    = (unsigned short*)alloc((size_t)2 * 8 * ROWSP * 128 * 2);

  FiltParams fp;
  {
    double step = 16.0 / 1023.0;
    int doff = 0;
    for (int i = 0; i < 8; ++i) {
      double t = (i == 7) ? 8.0 : (-1.0 + (double)i * (9.0 / 7.0));
      double s = pow(2.0, t);
      double stop = s * 16.0 + 1.0;
      int nmax = (int)ceil(stop);
      double sstep = s * step;
      int L = 0;
      for (int k = 0; k < nmax; ++k) {
        long j = (long)((double)k / sstep);
        if (j < 1024) L++; else break;
      }
      fp.L[i] = L;
      fp.off[i] = (L - 2) / 2;
      fp.doff[i] = doff;
      doff += L + 1 + 2 * FPAD;
    }
  }

  k_dft<<<dim3(NFREQ, 8), 128, 0, stream>>>(x, fl2d);
  k_ctrl<<<1, 256, 0, stream>>>(fl2d, b1, b2, ctrl, wsm, b1e, b2e);
  k_wprep<<<dim3(256, 128), 128, 0, stream>>>(W1, wl1, 256, 128);
  k_wprep<<<dim3(128, 256), 128, 0, stream>>>(W2, wl2, 128, 256);
  k_filt<<<8, 256, 0, stream>>>(filt, fp);
  k_cwt<<<dim3(42, 8, 8), 128, 0, stream>>>(x, filt, coefp, fp);
  k_xpad<<<dim3(QPB, 8), 128, 0, stream>>>(x, ctrl, xb0, xb1);

  // conv1 (mode 0): {coefp, xb0, xb1} -> {h1p, h1b0, h1b1}, gelu
  k_convm<<<576, 256, 0, stream>>>(coefp, xb0, xb1, wl1, b1e,
      h1p, h1b0, h1b1, (unsigned short*)nullptr, ctrl, 128, 256, QP_CWT, QPB, 1, 0);
  // conv2 (mode 1): {h1p, h1b0, h1b1} -> partial P
  k_convm<<<576, 256, 0, stream>>>(h1p, h1b0, h1b1, wl2, b2e,
      (unsigned short*)nullptr, (unsigned short*)nullptr, (unsigned short*)nullptr, P,
      ctrl, 256, 128, QP_CWT, QPB, 0, 1);

  k_combine<<<dim3(TT, 8), 128, 0, stream>>>(x, P, b2e, Wsc, bsc, wsm, ctrl, out);
}